// Round 2
// baseline (251.174 us; speedup 1.0000x reference)
//
#include <hip/hip_runtime.h>

// out[n,c,h,w] = sum_{c'} g[(c-c') mod 128] * act[n,c',h,w]
// where g = ifft(1 / fft(delta - k)), k = rolled zero-padded Ricker filter.
// C=128, S=H*W=4096 per image, 64 images -> 262144 spatial positions total.
//
// GEMM formulation with s on M, c on N (no LDS, no transpose):
//   D[m=s][n=c] = sum_{k=c'} X[c'][s] * G[c'][c],  G[k][n] = g[(n-k)&127]
// Per wave: one 16-s tile, all 128 c, K=128 -> 4 k-tiles x 8 n-tiles
// = 32 mfma_f32_16x16x32_bf16. G has only 8 distinct fragments since
// (16*nt - 32*kt) mod 128 depends only on (nt-2*kt)&7.

typedef short bf16x8 __attribute__((ext_vector_type(8)));
typedef float f32x4 __attribute__((ext_vector_type(4)));

#define MFMA16x16x32 __builtin_amdgcn_mfma_f32_16x16x32_bf16

__device__ __forceinline__ unsigned short f2bf(float f) {
  union { float f; unsigned u; } v; v.f = f;
  unsigned u = v.u;
  u += 0x7fffu + ((u >> 16) & 1u);   // round-to-nearest-even
  return (unsigned short)(u >> 16);
}

// ---------------------------------------------------------------------------
// Setup: compute g[128] (fp32) from the 27-tap filter. One block, 128 threads.
// kf[j] = filt[t] at j=(115+t)&127 (pad_left=50, roll by 65).
// Fk[m] = 1 - sum_t kf*e^{-2pi i j m/128};  g[n] = (1/128) Re sum_m e^{+2pi i mn/128}/Fk[m]
// ---------------------------------------------------------------------------
__global__ void build_g(const float* __restrict__ filt, float* __restrict__ g) {
  __shared__ float ct[128], st[128], fr[128], fi[128];
  const int t = threadIdx.x;  // 0..127
  const float ang = (float)t * 0.049087385212340526f;  // 2*pi/128
  float s, c;
  __sincosf(ang, &s, &c);
  ct[t] = c; st[t] = s;
  __syncthreads();

  // forward DFT of (delta - kf) at frequency m=t
  float re = 1.f, im = 0.f;
  for (int tt = 0; tt < 27; ++tt) {
    const int j = (115 + tt) & 127;
    const int idx = (j * t) & 127;
    const float kv = filt[tt];
    re -= kv * ct[idx];   // e^{-i a} = cos a - i sin a
    im += kv * st[idx];
  }
  fr[t] = re; fi[t] = im;
  __syncthreads();

  // inverse DFT of 1/Fk at position n=t (real part)
  float acc = 0.f;
  for (int m = 0; m < 128; ++m) {
    const int idx = (m * t) & 127;
    const float dr = fr[m], di = fi[m];
    acc += (ct[idx] * dr + st[idx] * di) / (dr * dr + di * di);
  }
  g[t] = acc * (1.0f / 128.0f);
}

// ---------------------------------------------------------------------------
// Main kernel: 4096 blocks x 256 threads (4 waves). Wave w owns the 16-s
// m-tile  mtile = blockIdx.x*4 + w.  No LDS, no barriers.
// ---------------------------------------------------------------------------
__global__ __launch_bounds__(256, 4) void conv_inhib(
    const float* __restrict__ X, const float* __restrict__ gtab,
    float* __restrict__ Y) {
  const int tid = threadIdx.x;
  const int l = tid & 63;
  const int w = tid >> 6;
  const int lane15 = l & 15;
  const int quad = l >> 4;

  const int mtile = (blockIdx.x << 2) + w;          // 0..16383
  const int sg = mtile << 4;                        // global s, multiple of 16
  const int img = sg >> 12;                         // 0..63
  const int spos = sg & 4095;                       // within-image s base

  const float* Xn = X + (size_t)img * (128 * 4096) + spos + lane15;
  float* Yn = Y + (size_t)img * (128 * 4096) + spos + (quad << 2);

  // ---- Build the 8 distinct G fragments: gf[d][lane,j] = g[(16d + n - k)&127]
  // with n = lane15, k = quad*8 + j  (B layout: B[k=quad*8+j][n=lane&15])
  bf16x8 gf[8];
#pragma unroll
  for (int d = 0; d < 8; ++d) {
    const int base = (d << 4) + lane15 - (quad << 3);
#pragma unroll
    for (int j = 0; j < 8; ++j) {
      gf[d][j] = (short)f2bf(gtab[(base - j) & 127]);
    }
  }

  // ---- K-loop: A[m=lane15][k=quad*8+j] = X[32kt + quad*8 + j][spos+lane15]
  f32x4 acc[8];
#pragma unroll
  for (int nt = 0; nt < 8; ++nt) acc[nt] = (f32x4){0.f, 0.f, 0.f, 0.f};

#pragma unroll
  for (int kt = 0; kt < 4; ++kt) {
    const float* Xk = Xn + (size_t)((kt << 5) + (quad << 3)) * 4096;
    float xa[8];
#pragma unroll
    for (int j = 0; j < 8; ++j) xa[j] = Xk[(size_t)j * 4096];
    bf16x8 af;
#pragma unroll
    for (int j = 0; j < 8; ++j) af[j] = (short)f2bf(xa[j]);
#pragma unroll
    for (int nt = 0; nt < 8; ++nt) {
      acc[nt] = MFMA16x16x32(af, gf[(nt - (kt << 1)) & 7], acc[nt], 0, 0, 0);
    }
  }

  // ---- Epilogue: lane holds D[s = quad*4 + r][c = 16nt + lane15], r=0..3
  // -> regs r are consecutive s: pack float4, each quad-group = one 64B line.
#pragma unroll
  for (int nt = 0; nt < 8; ++nt) {
    const int c = (nt << 4) + lane15;
    float4 v;
    v.x = acc[nt][0]; v.y = acc[nt][1]; v.z = acc[nt][2]; v.w = acc[nt][3];
    *(float4*)(Yn + (size_t)c * 4096) = v;
  }
}

extern "C" void kernel_launch(void* const* d_in, const int* in_sizes, int n_in,
                              void* d_out, int out_size, void* d_ws, size_t ws_size,
                              hipStream_t stream) {
  const float* act = (const float*)d_in[0];   // (64,128,64,64) fp32
  const float* filt = (const float*)d_in[1];  // 27 fp32
  float* out = (float*)d_out;                 // (64,128,64,64) fp32
  float* g = (float*)d_ws;                    // 128 fp32 scratch

  build_g<<<1, 128, 0, stream>>>(filt, g);
  conv_inhib<<<4096, 256, 0, stream>>>(act, g, out);
}

// Round 3
// 248.569 us; speedup vs baseline: 1.0105x; 1.0105x over previous
//
#include <hip/hip_runtime.h>

// out[n,c,h,w] = sum_{c'} g[(c-c') mod 128] * act[n,c',h,w]
// where g = ifft(1 / fft(delta - k)), k = rolled zero-padded Ricker filter.
// C=128, S=H*W=4096 per image, 64 images.
//
// GEMM with s on M, c on N:  D[m=s][n=c] = sum_k X[k][s] * G[k][n],
// G[k][n] = g[(n-k)&127] (circulant, only 8 distinct B-fragments).
// X staged to LDS via global_load_lds dwordx4 (no VGPR round trip, deep
// vmcnt queue), then per-wave A-fragments read from LDS.

typedef short bf16x8 __attribute__((ext_vector_type(8)));
typedef float f32x4 __attribute__((ext_vector_type(4)));

#define MFMA16x16x32 __builtin_amdgcn_mfma_f32_16x16x32_bf16

__device__ __forceinline__ unsigned short f2bf(float f) {
  union { float f; unsigned u; } v; v.f = f;
  unsigned u = v.u;
  u += 0x7fffu + ((u >> 16) & 1u);   // round-to-nearest-even
  return (unsigned short)(u >> 16);
}

// ---------------------------------------------------------------------------
// Setup: compute g[128] (fp32) from the 27-tap filter. One block, 128 threads.
// kf[j] = filt[t] at j=(115+t)&127 (pad_left=50, roll by 65).
// ---------------------------------------------------------------------------
__global__ void build_g(const float* __restrict__ filt, float* __restrict__ g) {
  __shared__ float ct[128], st[128], fr[128], fi[128];
  const int t = threadIdx.x;  // 0..127
  const float ang = (float)t * 0.049087385212340526f;  // 2*pi/128
  float s, c;
  __sincosf(ang, &s, &c);
  ct[t] = c; st[t] = s;
  __syncthreads();

  float re = 1.f, im = 0.f;
  for (int tt = 0; tt < 27; ++tt) {
    const int j = (115 + tt) & 127;
    const int idx = (j * t) & 127;
    const float kv = filt[tt];
    re -= kv * ct[idx];
    im += kv * st[idx];
  }
  fr[t] = re; fi[t] = im;
  __syncthreads();

  float acc = 0.f;
  for (int m = 0; m < 128; ++m) {
    const int idx = (m * t) & 127;
    const float dr = fr[m], di = fi[m];
    acc += (ct[idx] * dr + st[idx] * di) / (dr * dr + di * di);
  }
  g[t] = acc * (1.0f / 128.0f);
}

// ---------------------------------------------------------------------------
// Main kernel: 4096 blocks x 256 threads (4 waves). Block = one image n and
// one 64-wide s-tile; tile[c'=128][s=64] fp32 staged via global_load_lds.
// Wave w computes s in [16w, 16w+16), all 128 output c.
// ---------------------------------------------------------------------------
__global__ __launch_bounds__(256) void conv_inhib(
    const float* __restrict__ X, const float* __restrict__ gtab,
    float* __restrict__ Y) {
  __shared__ __align__(16) float tile[128 * 64];  // 32 KB, pitch 64 floats

  const int tid = threadIdx.x;
  const int l = tid & 63;
  const int w = tid >> 6;
  const int lane15 = l & 15;
  const int quad = l >> 4;

  const int bid = blockIdx.x;      // 0..4095
  const int img = bid >> 6;        // 0..63
  const int s0 = (bid & 63) << 6;  // s-tile origin (64 wide)

  const float* Xn = X + (size_t)img * (128 * 4096);
  float* Yn = Y + (size_t)img * (128 * 4096) + s0 + (w << 4) + (quad << 2);

  // ---- DMA stage: 32 x global_load_lds dwordx4 (8 per wave, 1 KB each).
  // Instr t covers rows 4t..4t+3: lane l -> row 4t + (l>>4), s chunk (l&15)*4.
  {
    const int rsub = l >> 4;            // 0..3
    const int soff = (l & 15) << 2;     // 0..60
#pragma unroll
    for (int i = 0; i < 8; ++i) {
      const int t = (w << 3) + i;       // 0..31
      const int r = (t << 2) + rsub;    // row c'
      const float* src = Xn + (size_t)r * 4096 + s0 + soff;
      float* dst = &tile[(t << 2) * 64];  // wave-uniform base; HW adds lane*16B
      __builtin_amdgcn_global_load_lds(
          (const __attribute__((address_space(1))) void*)src,
          (__attribute__((address_space(3))) void*)dst, 16, 0, 0);
    }
  }

  // ---- Build the 8 distinct G fragments while DMA is in flight:
  // gf[d][lane,j] = g[(16d + n - k)&127], n = lane15, k = quad*8 + j
  bf16x8 gf[8];
#pragma unroll
  for (int d = 0; d < 8; ++d) {
    const int base = (d << 4) + lane15 - (quad << 3);
#pragma unroll
    for (int j = 0; j < 8; ++j) {
      gf[d][j] = (short)f2bf(gtab[(base - j) & 127]);
    }
  }

  __syncthreads();

  // ---- GEMM: A[m=lane15][k=quad*8+j] = tile[kt*32 + quad*8 + j][16w + lane15]
  f32x4 acc[8];
#pragma unroll
  for (int nt = 0; nt < 8; ++nt) acc[nt] = (f32x4){0.f, 0.f, 0.f, 0.f};

#pragma unroll
  for (int kt = 0; kt < 4; ++kt) {
    const float* row = &tile[((kt << 5) + (quad << 3)) * 64 + (w << 4) + lane15];
    bf16x8 af;
#pragma unroll
    for (int j = 0; j < 8; ++j) af[j] = (short)f2bf(row[j * 64]);
#pragma unroll
    for (int nt = 0; nt < 8; ++nt) {
      acc[nt] = MFMA16x16x32(af, gf[(nt - (kt << 1)) & 7], acc[nt], 0, 0, 0);
    }
  }

  // ---- Epilogue: lane holds D[s = 16w + quad*4 + r][c = 16nt + lane15].
  // Regs r are 4 consecutive s -> one float4 store per (nt).
#pragma unroll
  for (int nt = 0; nt < 8; ++nt) {
    const int c = (nt << 4) + lane15;
    float4 v;
    v.x = acc[nt][0]; v.y = acc[nt][1]; v.z = acc[nt][2]; v.w = acc[nt][3];
    *(float4*)(Yn + (size_t)c * 4096) = v;
  }
}

extern "C" void kernel_launch(void* const* d_in, const int* in_sizes, int n_in,
                              void* d_out, int out_size, void* d_ws, size_t ws_size,
                              hipStream_t stream) {
  const float* act = (const float*)d_in[0];   // (64,128,64,64) fp32
  const float* filt = (const float*)d_in[1];  // 27 fp32
  float* out = (float*)d_out;                 // (64,128,64,64) fp32
  float* g = (float*)d_ws;                    // 128 fp32 scratch

  build_g<<<1, 128, 0, stream>>>(filt, g);
  conv_inhib<<<4096, 256, 0, stream>>>(act, g, out);
}